// Round 11
// baseline (254.761 us; speedup 1.0000x reference)
//
#include <hip/hip_runtime.h>
#include <hip/hip_bf16.h>

#define LRELU_SLOPE 0.2f
#define NB_SHIFT 7          // 128 dst-nodes per bucket
#define NBLK 512            // hist/partition parallel chunks

typedef __attribute__((ext_vector_type(8))) short short8;
typedef __attribute__((ext_vector_type(4))) float float4v;

// bf16 <-> fp32 helpers (raw ushort storage)
__device__ inline float b2f(unsigned short u) {
    union { unsigned int i; float f; } v; v.i = ((unsigned int)u) << 16; return v.f;
}
__device__ inline unsigned short f2b(float f) {
    union { float f; unsigned int i; } v; v.f = f;
    unsigned int x = v.i;
    unsigned int r = x + 0x7fffu + ((x >> 16) & 1u);   // round-to-nearest-even
    return (unsigned short)(r >> 16);
}
__device__ inline float lrelu(float x) { return x > 0.f ? x : LRELU_SLOPE * x; }

// ---------------------------------------------------------------------------
// GEMM1 (MFMA bf16) + fused dots1 + fused CSR hist (blocks < NBLK).
// Also zeroes the scanAB done-counter (stream order guarantees visibility).
// ---------------------------------------------------------------------------
__global__ __launch_bounds__(256) void gemm1_mfma_kernel(
        const float* __restrict__ x, const float* __restrict__ W1,
        const float* __restrict__ a_src, const float* __restrict__ a_dst,
        unsigned short* __restrict__ h1b, float* __restrict__ es,
        float* __restrict__ ed, int N,
        const int* __restrict__ dst, int E, int Etot, int nb, int chunk,
        int* __restrict__ cnt, int* __restrict__ done_ctr) {
    __shared__ unsigned short xs[64][136];
    __shared__ unsigned short wt[128][136];
    int tid = threadIdx.x;
    int n0 = blockIdx.x * 64;
    if (blockIdx.x == 0 && tid == 0) done_ctr[0] = 0;

    for (int i = tid; i < 128 * 128; i += 256) {
        int k = i >> 7, n = i & 127;
        wt[n][k] = f2b(W1[i]);
    }
    {
        int rows = N - n0; if (rows > 64) rows = 64;
        const float4* xv = (const float4*)(x + (size_t)n0 * 128);
        int lim = rows * 32;                 // float4 count
        for (int i = tid; i < lim; i += 256) {
            float4 v = xv[i];
            int r = i >> 5, c4 = (i & 31) << 2;
            uint2 p;
            p.x = (unsigned int)f2b(v.x) | ((unsigned int)f2b(v.y) << 16);
            p.y = (unsigned int)f2b(v.z) | ((unsigned int)f2b(v.w) << 16);
            *(uint2*)&xs[r][c4] = p;
        }
    }
    __syncthreads();

    int wave = tid >> 6;
    int lane = tid & 63;
    int lrow = lane & 15;
    int quad = lane >> 4;

    short8 afr[4];
#pragma unroll
    for (int kc = 0; kc < 4; kc++)
        afr[kc] = *(const short8*)&xs[wave * 16 + lrow][kc * 32 + quad * 8];
    __syncthreads();   // all waves' A-fragment reads done before xs is reused

#pragma unroll
    for (int ct = 0; ct < 8; ct++) {
        float4v acc = {0.f, 0.f, 0.f, 0.f};
#pragma unroll
        for (int kc = 0; kc < 4; kc++) {
            short8 bfr = *(const short8*)&wt[ct * 16 + lrow][kc * 32 + quad * 8];
            acc = __builtin_amdgcn_mfma_f32_16x16x32_bf16(afr[kc], bfr, acc, 0, 0, 0);
        }
#pragma unroll
        for (int r = 0; r < 4; r++) {
            int lr = wave * 16 + quad * 4 + r;
            int grow = n0 + lr;
            unsigned short hb = f2b(acc[r]);
            xs[lr][ct * 16 + lrow] = hb;           // stage result tile for dots
            if (grow < N)
                h1b[grow * 128 + ct * 16 + lrow] = hb;
        }
    }
    __syncthreads();   // xs result tile ready; wt reads done (reused below)

    // fused dots1: thread = (row, head); 32-channel dot per head
    int row = tid >> 2, h = tid & 3;
    int rg = n0 + row;
    if (rg < N) {
        const float* ap = a_src + h * 32;
        const float* bp = a_dst + h * 32;
        float s = 0.f, d = 0.f;
#pragma unroll
        for (int c2 = 0; c2 < 16; c2++) {
            unsigned int u = *(const unsigned int*)&xs[row][h * 32 + 2 * c2];
            float v0 = b2f((unsigned short)(u & 0xffffu));
            float v1 = b2f((unsigned short)(u >> 16));
            float2 a = *(const float2*)&ap[2 * c2];
            float2 b = *(const float2*)&bp[2 * c2];
            s += v0 * a.x + v1 * a.y;
            d += v0 * b.x + v1 * b.y;
        }
        es[rg * 4 + h] = s;
        ed[rg * 4 + h] = d;
    }

    // fused CSR histogram (reuses wt LDS; all threads hit the barriers)
    int* histm = (int*)&wt[0][0];
    int blk = blockIdx.x;
    if (blk < NBLK)
        for (int i = tid; i < nb; i += 256) histm[i] = 0;
    __syncthreads();
    if (blk < NBLK) {
        int lo = blk * chunk;
        int hi = lo + chunk; if (hi > Etot) hi = Etot;
        for (int i = lo + tid; i < hi; i += 256) {
            int d = (i < E) ? dst[i] : (i - E);
            atomicAdd(&histm[d >> NB_SHIFT], 1);
        }
    }
    __syncthreads();
    if (blk < NBLK)
        for (int b = tid; b < nb; b += 256)
            cnt[b * NBLK + blk] = histm[b];
}

// ---------------------------------------------------------------------------
// Fused two-level scan: block-local exclusive scan of cnt + block totals to
// bsum; LAST block (atomic ticket) then exclusive-scans bsum in place.
// Consumers read cnt[i] + bsum[i>>10].
// ---------------------------------------------------------------------------
__global__ __launch_bounds__(1024) void scanAB_kernel(int* cnt, int* bsum, int M,
                                                      int nbA, int* done_ctr) {
    __shared__ int tile[1024];
    __shared__ int amLast;
    int i = blockIdx.x * 1024 + threadIdx.x;
    int v = (i < M) ? cnt[i] : 0;
    tile[threadIdx.x] = v;
    __syncthreads();
    for (int off = 1; off < 1024; off <<= 1) {
        int t = (threadIdx.x >= (unsigned)off) ? tile[threadIdx.x - off] : 0;
        __syncthreads();
        tile[threadIdx.x] += t;
        __syncthreads();
    }
    int incl = tile[threadIdx.x];
    if (i < M) cnt[i] = incl - v;
    if (threadIdx.x == 1023) bsum[blockIdx.x] = incl;
    __threadfence();
    if (threadIdx.x == 0)
        amLast = (atomicAdd(done_ctr, 1) == (int)gridDim.x - 1);
    __syncthreads();
    if (amLast) {
        int vv = (threadIdx.x < (unsigned)nbA) ? bsum[threadIdx.x] : 0;
        tile[threadIdx.x] = vv;
        __syncthreads();
        for (int off = 1; off < 1024; off <<= 1) {
            int t = (threadIdx.x >= (unsigned)off) ? tile[threadIdx.x - off] : 0;
            __syncthreads();
            tile[threadIdx.x] += t;
            __syncthreads();
        }
        if (threadIdx.x < (unsigned)nbA) bsum[threadIdx.x] = tile[threadIdx.x] - vv;
    }
}

// ---------------------------------------------------------------------------
// CSR build, pass 2: partition edges into bucket array (no global atomics).
// ---------------------------------------------------------------------------
__global__ __launch_bounds__(256) void partition_kernel(
        const int* __restrict__ src, const int* __restrict__ dst,
        int E, int Etot, int nb, int chunk,
        const int* __restrict__ cnt, const int* __restrict__ boff,
        int2* __restrict__ bkt) {
    __shared__ int cur[512];
    int blk = blockIdx.x;
    for (int b = threadIdx.x; b < nb; b += 256) {
        int idx = b * NBLK + blk;
        cur[b] = cnt[idx] + boff[idx >> 10];
    }
    __syncthreads();
    int lo = blk * chunk;
    int hi = lo + chunk; if (hi > Etot) hi = Etot;
    for (int i = lo + threadIdx.x; i < hi; i += 256) {
        int s, d;
        if (i < E) { s = src[i]; d = dst[i]; }
        else       { s = d = i - E; }
        int pos = atomicAdd(&cur[d >> NB_SHIFT], 1);
        bkt[pos] = make_int2(s, d);
    }
}

// ---------------------------------------------------------------------------
// CSR build, pass 3 (one block per bucket): degree count -> LDS scan -> ptr;
// place src indices at final CSR positions; fold in fp16 layer-1 edge weights
// (linear w1h stream is cheap for agg1 to read — R10 showed inline weights
// in agg1's hot loop regress by ~19 µs).
// ---------------------------------------------------------------------------
__global__ __launch_bounds__(256) void finalize_kernel(
        const int2* __restrict__ bkt, const int* __restrict__ cnt,
        const int* __restrict__ boff, int nb,
        const float* __restrict__ es, const float* __restrict__ ed,
        int* __restrict__ ptr, int* __restrict__ csr_src,
        _Float16* __restrict__ w1h, int N, int Etot) {
    __shared__ int deg[128];
    __shared__ int scn[128];
    __shared__ int cur[128];
    int b = blockIdx.x;
    int idx0 = b * NBLK;
    int base = cnt[idx0] + boff[idx0 >> 10];
    int nextbase;
    if (b + 1 < nb) {
        int idx1 = (b + 1) * NBLK;
        nextbase = cnt[idx1] + boff[idx1 >> 10];
    } else nextbase = Etot;
    int count = nextbase - base;
    int node0 = b << NB_SHIFT;
    int nodes = N - node0; if (nodes > 128) nodes = 128;

    if (threadIdx.x < 128) deg[threadIdx.x] = 0;
    __syncthreads();
    for (int i = threadIdx.x; i < count; i += 256)
        atomicAdd(&deg[bkt[base + i].y - node0], 1);
    __syncthreads();
    int v = (threadIdx.x < 128) ? deg[threadIdx.x] : 0;
    if (threadIdx.x < 128) scn[threadIdx.x] = v;
    __syncthreads();
    for (int off = 1; off < 128; off <<= 1) {
        int t = (threadIdx.x < 128 && threadIdx.x >= (unsigned)off) ? scn[threadIdx.x - off] : 0;
        __syncthreads();
        if (threadIdx.x < 128) scn[threadIdx.x] += t;
        __syncthreads();
    }
    if (threadIdx.x < 128) {
        int excl = scn[threadIdx.x] - v;
        cur[threadIdx.x] = excl;
        if (threadIdx.x < nodes) ptr[node0 + threadIdx.x] = base + excl;
    }
    if (b == nb - 1 && threadIdx.x == 0) ptr[N] = Etot;
    __syncthreads();
    for (int i = threadIdx.x; i < count; i += 256) {
        int2 sd = bkt[base + i];
        int pos = base + atomicAdd(&cur[sd.y - node0], 1);
        csr_src[pos] = sd.x;
        float4 a = *(const float4*)&es[sd.x * 4];
        float4 bb = *(const float4*)&ed[sd.y * 4];
        union { _Float16 h[4]; uint2 u; } ww;
        ww.h[0] = (_Float16)__expf(lrelu(a.x + bb.x));
        ww.h[1] = (_Float16)__expf(lrelu(a.y + bb.y));
        ww.h[2] = (_Float16)__expf(lrelu(a.z + bb.z));
        ww.h[3] = (_Float16)__expf(lrelu(a.w + bb.w));
        *(uint2*)&w1h[(size_t)pos * 4] = ww.u;
    }
}

// ---------------------------------------------------------------------------
// GEMM2 (MFMA bf16) + fused dots2: h2b = bf16(h1e @ W2); es2/ed2 per row.
// ---------------------------------------------------------------------------
__global__ __launch_bounds__(256) void gemm2_mfma_kernel(
        const unsigned short* __restrict__ h1e, const float* __restrict__ W2,
        const float* __restrict__ a_src, const float* __restrict__ a_dst,
        unsigned short* __restrict__ h2b, float* __restrict__ es,
        float* __restrict__ ed, int N) {
    __shared__ unsigned short xs[64][136];
    __shared__ unsigned short wt[32][136];
    int tid = threadIdx.x;
    int n0 = blockIdx.x * 64;

    for (int i = tid; i < 128 * 32; i += 256) {
        int k = i >> 5, n = i & 31;
        wt[n][k] = f2b(W2[i]);
    }
    {
        const unsigned int* srcp = (const unsigned int*)(h1e + (size_t)n0 * 128);
        int rows = (N - n0) < 64 ? (N - n0) : 64;
        int maxu = rows * 64;
        for (int i = tid; i < 4096; i += 256) {
            unsigned int v = (i < maxu) ? srcp[i] : 0u;
            int r = i >> 6, cp = (i & 63) << 1;
            *(unsigned int*)&xs[r][cp] = v;
        }
    }
    __syncthreads();

    int wave = tid >> 6;
    int lane = tid & 63;
    int lrow = lane & 15;
    int quad = lane >> 4;

    short8 afr[4];
#pragma unroll
    for (int kc = 0; kc < 4; kc++)
        afr[kc] = *(const short8*)&xs[wave * 16 + lrow][kc * 32 + quad * 8];
    __syncthreads();

#pragma unroll
    for (int ct = 0; ct < 2; ct++) {
        float4v acc = {0.f, 0.f, 0.f, 0.f};
#pragma unroll
        for (int kc = 0; kc < 4; kc++) {
            short8 bfr = *(const short8*)&wt[ct * 16 + lrow][kc * 32 + quad * 8];
            acc = __builtin_amdgcn_mfma_f32_16x16x32_bf16(afr[kc], bfr, acc, 0, 0, 0);
        }
#pragma unroll
        for (int r = 0; r < 4; r++) {
            int lr = wave * 16 + quad * 4 + r;
            int grow = n0 + lr;
            unsigned short hb = f2b(acc[r]);
            xs[lr][ct * 16 + lrow] = hb;
            if (grow < N)
                h2b[(size_t)grow * 32 + ct * 16 + lrow] = hb;
        }
    }
    __syncthreads();

    // fused dots2 (1 head, 32 channels): threads 0..63 = rows
    if (tid < 64) {
        int rg = n0 + tid;
        if (rg < N) {
            float s = 0.f, d = 0.f;
#pragma unroll
            for (int c2 = 0; c2 < 16; c2++) {
                unsigned int u = *(const unsigned int*)&xs[tid][2 * c2];
                float v0 = b2f((unsigned short)(u & 0xffffu));
                float v1 = b2f((unsigned short)(u >> 16));
                float2 a = *(const float2*)&a_src[2 * c2];
                float2 b = *(const float2*)&a_dst[2 * c2];
                s += v0 * a.x + v1 * a.y;
                d += v0 * b.x + v1 * b.y;
            }
            es[rg] = s;
            ed[rg] = d;
        }
    }
}

// ---------------------------------------------------------------------------
// Aggregation layer 1: 16 lanes/node x 8 channels (uint4 = 16 B/lane),
// 4 nodes/wave, 16/block; linear fp16 weight stream (w1h).
// ---------------------------------------------------------------------------
__global__ __launch_bounds__(256) void agg1_kernel(
        const uint4* __restrict__ h1v, const _Float16* __restrict__ w1h,
        const int* __restrict__ csr, const int* __restrict__ ptr,
        const float* __restrict__ b1, uint4* __restrict__ h1e_v, int N) {
    int tid = threadIdx.x;
    int n = blockIdx.x * 16 + (tid >> 4);
    if (n >= N) return;
    int cl = tid & 15;           // 16-B granule: channels 8cl..8cl+7
    int h = cl >> 2;             // head
    int start = ptr[n], end = ptr[n + 1];
    float a0 = 0.f, a1 = 0.f, a2 = 0.f, a3 = 0.f;
    float a4 = 0.f, a5 = 0.f, a6 = 0.f, a7 = 0.f, ws = 0.f;
    int i = start;
    for (; i + 4 <= end; i += 4) {
        int s[4]; float v[4]; uint4 g[4];
#pragma unroll
        for (int k = 0; k < 4; k++) s[k] = csr[i + k];
#pragma unroll
        for (int k = 0; k < 4; k++) v[k] = (float)w1h[(size_t)(i + k) * 4 + h];
#pragma unroll
        for (int k = 0; k < 4; k++) g[k] = h1v[(s[k] << 4) + cl];
#pragma unroll
        for (int k = 0; k < 4; k++) {
            a0 += v[k] * b2f((unsigned short)(g[k].x & 0xffffu));
            a1 += v[k] * b2f((unsigned short)(g[k].x >> 16));
            a2 += v[k] * b2f((unsigned short)(g[k].y & 0xffffu));
            a3 += v[k] * b2f((unsigned short)(g[k].y >> 16));
            a4 += v[k] * b2f((unsigned short)(g[k].z & 0xffffu));
            a5 += v[k] * b2f((unsigned short)(g[k].z >> 16));
            a6 += v[k] * b2f((unsigned short)(g[k].w & 0xffffu));
            a7 += v[k] * b2f((unsigned short)(g[k].w >> 16));
            ws += v[k];
        }
    }
    for (; i < end; i++) {
        int s = csr[i];
        float v = (float)w1h[(size_t)i * 4 + h];
        uint4 g = h1v[(s << 4) + cl];
        a0 += v * b2f((unsigned short)(g.x & 0xffffu));
        a1 += v * b2f((unsigned short)(g.x >> 16));
        a2 += v * b2f((unsigned short)(g.y & 0xffffu));
        a3 += v * b2f((unsigned short)(g.y >> 16));
        a4 += v * b2f((unsigned short)(g.z & 0xffffu));
        a5 += v * b2f((unsigned short)(g.z >> 16));
        a6 += v * b2f((unsigned short)(g.w & 0xffffu));
        a7 += v * b2f((unsigned short)(g.w >> 16));
        ws += v;
    }
    float r = 1.f / ws;
    float4 bb0 = ((const float4*)b1)[cl * 2];
    float4 bb1 = ((const float4*)b1)[cl * 2 + 1];
    float o0 = a0 * r + bb0.x;
    float o1 = a1 * r + bb0.y;
    float o2 = a2 * r + bb0.z;
    float o3 = a3 * r + bb0.w;
    float o4 = a4 * r + bb1.x;
    float o5 = a5 * r + bb1.y;
    float o6 = a6 * r + bb1.z;
    float o7 = a7 * r + bb1.w;
    o0 = o0 > 0.f ? o0 : __expf(o0) - 1.f;
    o1 = o1 > 0.f ? o1 : __expf(o1) - 1.f;
    o2 = o2 > 0.f ? o2 : __expf(o2) - 1.f;
    o3 = o3 > 0.f ? o3 : __expf(o3) - 1.f;
    o4 = o4 > 0.f ? o4 : __expf(o4) - 1.f;
    o5 = o5 > 0.f ? o5 : __expf(o5) - 1.f;
    o6 = o6 > 0.f ? o6 : __expf(o6) - 1.f;
    o7 = o7 > 0.f ? o7 : __expf(o7) - 1.f;
    uint4 outv;
    outv.x = (unsigned int)f2b(o0) | ((unsigned int)f2b(o1) << 16);
    outv.y = (unsigned int)f2b(o2) | ((unsigned int)f2b(o3) << 16);
    outv.z = (unsigned int)f2b(o4) | ((unsigned int)f2b(o5) << 16);
    outv.w = (unsigned int)f2b(o6) | ((unsigned int)f2b(o7) << 16);
    h1e_v[(n << 4) + cl] = outv;
}

// ---------------------------------------------------------------------------
// Aggregation layer 2: 8 lanes/node x 4 channels (uint2 = one 64-B line per
// edge), 8 nodes/wave, 32/block; unroll x8; inline exp weights.
// ---------------------------------------------------------------------------
__global__ __launch_bounds__(256) void agg2_kernel(
        const uint2* __restrict__ h2v, const float* __restrict__ es,
        const float* __restrict__ ed, const int* __restrict__ csr,
        const int* __restrict__ ptr, const float* __restrict__ b2,
        float* __restrict__ out, int N) {
    int tid = threadIdx.x;
    int n = blockIdx.x * 32 + (tid >> 3);
    if (n >= N) return;
    int cl = tid & 7;            // channels 4cl..4cl+3
    float edl = ed[n];
    int start = ptr[n], end = ptr[n + 1];
    float a0 = 0.f, a1 = 0.f, a2 = 0.f, a3 = 0.f, ws = 0.f;
    int i = start;
    for (; i + 8 <= end; i += 8) {
        int s[8]; float e[8]; uint2 g[8];
#pragma unroll
        for (int k = 0; k < 8; k++) s[k] = csr[i + k];
#pragma unroll
        for (int k = 0; k < 8; k++) e[k] = es[s[k]];
#pragma unroll
        for (int k = 0; k < 8; k++) g[k] = h2v[(s[k] << 3) + cl];
#pragma unroll
        for (int k = 0; k < 8; k++) {
            float v = __expf(lrelu(e[k] + edl));
            a0 += v * b2f((unsigned short)(g[k].x & 0xffffu));
            a1 += v * b2f((unsigned short)(g[k].x >> 16));
            a2 += v * b2f((unsigned short)(g[k].y & 0xffffu));
            a3 += v * b2f((unsigned short)(g[k].y >> 16));
            ws += v;
        }
    }
    for (; i < end; i++) {
        int s = csr[i];
        float v = __expf(lrelu(es[s] + edl));
        uint2 g = h2v[(s << 3) + cl];
        a0 += v * b2f((unsigned short)(g.x & 0xffffu));
        a1 += v * b2f((unsigned short)(g.x >> 16));
        a2 += v * b2f((unsigned short)(g.y & 0xffffu));
        a3 += v * b2f((unsigned short)(g.y >> 16));
        ws += v;
    }
    float r = 1.f / ws;
    float4 bb = ((const float4*)b2)[cl];
    float4 o;
    o.x = a0 * r + bb.x;
    o.y = a1 * r + bb.y;
    o.z = a2 * r + bb.z;
    o.w = a3 * r + bb.w;
    ((float4*)out)[(size_t)n * 8 + cl] = o;
}

// ---------------------------------------------------------------------------
extern "C" void kernel_launch(void* const* d_in, const int* in_sizes, int n_in,
                              void* d_out, int out_size, void* d_ws, size_t ws_size,
                              hipStream_t stream) {
    const float* x      = (const float*)d_in[0];
    const int*   ei     = (const int*)  d_in[1];
    const float* W1     = (const float*)d_in[2];
    const float* a_src1 = (const float*)d_in[3];
    const float* a_dst1 = (const float*)d_in[4];
    const float* b1     = (const float*)d_in[5];
    const float* W2     = (const float*)d_in[6];
    const float* a_src2 = (const float*)d_in[7];
    const float* a_dst2 = (const float*)d_in[8];
    const float* b2     = (const float*)d_in[9];
    float* outp = (float*)d_out;

    const int N = in_sizes[0] / 128;   // 50000
    const int E = in_sizes[1] / 2;     // 800000
    const int Etot = E + N;            // 850000

    const int* src = ei;
    const int* dst = ei + E;

    const int nb    = (N + 127) >> 7;                // 391 buckets
    const int chunk = (Etot + NBLK - 1) / NBLK;      // 1661
    const int M = nb * NBLK;                         // 200192 scan elements
    const int nbA = (M + 1023) / 1024;               // 196

    // workspace layout (bytes); total ~48.8 MB
    char* w = (char*)d_ws;
    unsigned short* h1b = (unsigned short*)(w + 0);          // 12,800,000
    unsigned short* h1e = (unsigned short*)(w + 12800000);   // 12,800,000
    unsigned short* h2b = (unsigned short*)(w + 25600000);   //  3,200,000
    float* es1  = (float*)(w + 28800000);                    //    800,000
    float* ed1  = (float*)(w + 29600000);                    //    800,000
    float* es2  = (float*)(w + 30400000);                    //    200,000
    float* ed2  = (float*)(w + 30600000);                    //    200,000
    int*   ptr  = (int*)  (w + 30800000);                    //    200,064
    int*   bsum = (int*)  (w + 31000064);                    //      1,024
    int*   done = (int*)  (w + 31001088);                    //         64
    int*   cnt  = (int*)  (w + 31001152);                    //    800,768
    int*   csr_src = (int*)(w + 31801920);                   //  3,400,000
    int2*  bkt  = (int2*) (w + 35201920);                    //  6,800,000
    _Float16* w1h = (_Float16*)(w + 42001920);               //  6,800,000 -> 48,801,920

    // --- Layer-1 GEMM + fused dots1 + fused hist (+ done-counter reset) ---
    gemm1_mfma_kernel<<<(N + 63) / 64, 256, 0, stream>>>(x, W1, a_src1, a_dst1,
                                                         h1b, es1, ed1, N,
                                                         dst, E, Etot, nb, chunk,
                                                         cnt, done);

    // --- CSR build: fused two-level scan -> partition -> finalize ---
    scanAB_kernel<<<nbA, 1024, 0, stream>>>(cnt, bsum, M, nbA, done);
    partition_kernel<<<NBLK, 256, 0, stream>>>(src, dst, E, Etot, nb, chunk,
                                               cnt, bsum, bkt);
    finalize_kernel<<<nb, 256, 0, stream>>>(bkt, cnt, bsum, nb, es1, ed1,
                                            ptr, csr_src, w1h, N, Etot);

    // --- Layer 1 aggregate (linear fp16 weight stream) ---
    agg1_kernel<<<(N + 15) / 16, 256, 0, stream>>>((const uint4*)h1b, w1h,
                                                   csr_src, ptr, b1,
                                                   (uint4*)h1e, N);

    // --- Layer 2: GEMM + fused dots, then aggregate with inline weights ---
    gemm2_mfma_kernel<<<(N + 63) / 64, 256, 0, stream>>>(h1e, W2, a_src2, a_dst2,
                                                         h2b, es2, ed2, N);
    agg2_kernel<<<(N + 31) / 32, 256, 0, stream>>>((const uint2*)h2b, es2, ed2,
                                                   csr_src, ptr, b2, outp, N);
}

// Round 12
// 198.250 us; speedup vs baseline: 1.2850x; 1.2850x over previous
//
#include <hip/hip_runtime.h>
#include <hip/hip_bf16.h>

#define LRELU_SLOPE 0.2f
#define NB_SHIFT 7          // 128 dst-nodes per bucket
#define NBLK 512            // hist/partition parallel chunks

typedef __attribute__((ext_vector_type(8))) short short8;
typedef __attribute__((ext_vector_type(4))) float float4v;

// bf16 <-> fp32 helpers (raw ushort storage)
__device__ inline float b2f(unsigned short u) {
    union { unsigned int i; float f; } v; v.i = ((unsigned int)u) << 16; return v.f;
}
__device__ inline unsigned short f2b(float f) {
    union { float f; unsigned int i; } v; v.f = f;
    unsigned int x = v.i;
    unsigned int r = x + 0x7fffu + ((x >> 16) & 1u);   // round-to-nearest-even
    return (unsigned short)(r >> 16);
}
__device__ inline float lrelu(float x) { return x > 0.f ? x : LRELU_SLOPE * x; }

// ---------------------------------------------------------------------------
// GEMM1 (MFMA bf16) + fused dots1 + fused CSR hist (blocks < NBLK).
// ---------------------------------------------------------------------------
__global__ __launch_bounds__(256) void gemm1_mfma_kernel(
        const float* __restrict__ x, const float* __restrict__ W1,
        const float* __restrict__ a_src, const float* __restrict__ a_dst,
        unsigned short* __restrict__ h1b, float* __restrict__ es,
        float* __restrict__ ed, int N,
        const int* __restrict__ dst, int E, int Etot, int nb, int chunk,
        int* __restrict__ cnt) {
    __shared__ unsigned short xs[64][136];
    __shared__ unsigned short wt[128][136];
    int tid = threadIdx.x;
    int n0 = blockIdx.x * 64;

    for (int i = tid; i < 128 * 128; i += 256) {
        int k = i >> 7, n = i & 127;
        wt[n][k] = f2b(W1[i]);
    }
    {
        int rows = N - n0; if (rows > 64) rows = 64;
        const float4* xv = (const float4*)(x + (size_t)n0 * 128);
        int lim = rows * 32;                 // float4 count
        for (int i = tid; i < lim; i += 256) {
            float4 v = xv[i];
            int r = i >> 5, c4 = (i & 31) << 2;
            uint2 p;
            p.x = (unsigned int)f2b(v.x) | ((unsigned int)f2b(v.y) << 16);
            p.y = (unsigned int)f2b(v.z) | ((unsigned int)f2b(v.w) << 16);
            *(uint2*)&xs[r][c4] = p;
        }
    }
    __syncthreads();

    int wave = tid >> 6;
    int lane = tid & 63;
    int lrow = lane & 15;
    int quad = lane >> 4;

    short8 afr[4];
#pragma unroll
    for (int kc = 0; kc < 4; kc++)
        afr[kc] = *(const short8*)&xs[wave * 16 + lrow][kc * 32 + quad * 8];
    __syncthreads();   // all waves' A-fragment reads done before xs is reused

#pragma unroll
    for (int ct = 0; ct < 8; ct++) {
        float4v acc = {0.f, 0.f, 0.f, 0.f};
#pragma unroll
        for (int kc = 0; kc < 4; kc++) {
            short8 bfr = *(const short8*)&wt[ct * 16 + lrow][kc * 32 + quad * 8];
            acc = __builtin_amdgcn_mfma_f32_16x16x32_bf16(afr[kc], bfr, acc, 0, 0, 0);
        }
#pragma unroll
        for (int r = 0; r < 4; r++) {
            int lr = wave * 16 + quad * 4 + r;
            int grow = n0 + lr;
            unsigned short hb = f2b(acc[r]);
            xs[lr][ct * 16 + lrow] = hb;           // stage result tile for dots
            if (grow < N)
                h1b[grow * 128 + ct * 16 + lrow] = hb;
        }
    }
    __syncthreads();   // xs result tile ready; wt reads done (reused below)

    // fused dots1: thread = (row, head); 32-channel dot per head
    int row = tid >> 2, h = tid & 3;
    int rg = n0 + row;
    if (rg < N) {
        const float* ap = a_src + h * 32;
        const float* bp = a_dst + h * 32;
        float s = 0.f, d = 0.f;
#pragma unroll
        for (int c2 = 0; c2 < 16; c2++) {
            unsigned int u = *(const unsigned int*)&xs[row][h * 32 + 2 * c2];
            float v0 = b2f((unsigned short)(u & 0xffffu));
            float v1 = b2f((unsigned short)(u >> 16));
            float2 a = *(const float2*)&ap[2 * c2];
            float2 b = *(const float2*)&bp[2 * c2];
            s += v0 * a.x + v1 * a.y;
            d += v0 * b.x + v1 * b.y;
        }
        es[rg * 4 + h] = s;
        ed[rg * 4 + h] = d;
    }

    // fused CSR histogram (reuses wt LDS; all threads hit the barriers)
    int* histm = (int*)&wt[0][0];
    int blk = blockIdx.x;
    if (blk < NBLK)
        for (int i = tid; i < nb; i += 256) histm[i] = 0;
    __syncthreads();
    if (blk < NBLK) {
        int lo = blk * chunk;
        int hi = lo + chunk; if (hi > Etot) hi = Etot;
        for (int i = lo + tid; i < hi; i += 256) {
            int d = (i < E) ? dst[i] : (i - E);
            atomicAdd(&histm[d >> NB_SHIFT], 1);
        }
    }
    __syncthreads();
    if (blk < NBLK)
        for (int b = tid; b < nb; b += 256)
            cnt[b * NBLK + blk] = histm[b];
}

// ---------------------------------------------------------------------------
// Two-level scan as two kernels (R9 structure). NO device fences: the
// kernel-boundary ordering provides cross-XCD visibility for free.
// (R11's fused scanAB with __threadfence stalled 57 µs — fence drains L2.)
// ---------------------------------------------------------------------------
__global__ __launch_bounds__(1024) void scanA_kernel(int* cnt, int* bsum, int M) {
    __shared__ int tile[1024];
    int i = blockIdx.x * 1024 + threadIdx.x;
    int v = (i < M) ? cnt[i] : 0;
    tile[threadIdx.x] = v;
    __syncthreads();
    for (int off = 1; off < 1024; off <<= 1) {
        int t = (threadIdx.x >= (unsigned)off) ? tile[threadIdx.x - off] : 0;
        __syncthreads();
        tile[threadIdx.x] += t;
        __syncthreads();
    }
    int incl = tile[threadIdx.x];
    if (i < M) cnt[i] = incl - v;
    if (threadIdx.x == 1023) bsum[blockIdx.x] = incl;
}

__global__ __launch_bounds__(256) void scanB_kernel(int* __restrict__ bsum, int nb) {
    __shared__ int tile[256];
    int v = (threadIdx.x < (unsigned)nb) ? bsum[threadIdx.x] : 0;
    tile[threadIdx.x] = v;
    __syncthreads();
    for (int off = 1; off < 256; off <<= 1) {
        int t = (threadIdx.x >= (unsigned)off) ? tile[threadIdx.x - off] : 0;
        __syncthreads();
        tile[threadIdx.x] += t;
        __syncthreads();
    }
    if (threadIdx.x < (unsigned)nb) bsum[threadIdx.x] = tile[threadIdx.x] - v;
}

// ---------------------------------------------------------------------------
// CSR build, pass 2: partition edges into bucket array (no global atomics).
// ---------------------------------------------------------------------------
__global__ __launch_bounds__(256) void partition_kernel(
        const int* __restrict__ src, const int* __restrict__ dst,
        int E, int Etot, int nb, int chunk,
        const int* __restrict__ cnt, const int* __restrict__ boff,
        int2* __restrict__ bkt) {
    __shared__ int cur[512];
    int blk = blockIdx.x;
    for (int b = threadIdx.x; b < nb; b += 256) {
        int idx = b * NBLK + blk;
        cur[b] = cnt[idx] + boff[idx >> 10];
    }
    __syncthreads();
    int lo = blk * chunk;
    int hi = lo + chunk; if (hi > Etot) hi = Etot;
    for (int i = lo + threadIdx.x; i < hi; i += 256) {
        int s, d;
        if (i < E) { s = src[i]; d = dst[i]; }
        else       { s = d = i - E; }
        int pos = atomicAdd(&cur[d >> NB_SHIFT], 1);
        bkt[pos] = make_int2(s, d);
    }
}

// ---------------------------------------------------------------------------
// CSR build, pass 3 (one block per bucket): degree count -> LDS scan -> ptr;
// place src indices at final CSR positions; fold in fp16 layer-1 edge weights
// (linear w1h stream is cheap for agg1 to read — R10 showed inline weights
// in agg1's hot loop regress).
// ---------------------------------------------------------------------------
__global__ __launch_bounds__(256) void finalize_kernel(
        const int2* __restrict__ bkt, const int* __restrict__ cnt,
        const int* __restrict__ boff, int nb,
        const float* __restrict__ es, const float* __restrict__ ed,
        int* __restrict__ ptr, int* __restrict__ csr_src,
        _Float16* __restrict__ w1h, int N, int Etot) {
    __shared__ int deg[128];
    __shared__ int scn[128];
    __shared__ int cur[128];
    int b = blockIdx.x;
    int idx0 = b * NBLK;
    int base = cnt[idx0] + boff[idx0 >> 10];
    int nextbase;
    if (b + 1 < nb) {
        int idx1 = (b + 1) * NBLK;
        nextbase = cnt[idx1] + boff[idx1 >> 10];
    } else nextbase = Etot;
    int count = nextbase - base;
    int node0 = b << NB_SHIFT;
    int nodes = N - node0; if (nodes > 128) nodes = 128;

    if (threadIdx.x < 128) deg[threadIdx.x] = 0;
    __syncthreads();
    for (int i = threadIdx.x; i < count; i += 256)
        atomicAdd(&deg[bkt[base + i].y - node0], 1);
    __syncthreads();
    int v = (threadIdx.x < 128) ? deg[threadIdx.x] : 0;
    if (threadIdx.x < 128) scn[threadIdx.x] = v;
    __syncthreads();
    for (int off = 1; off < 128; off <<= 1) {
        int t = (threadIdx.x < 128 && threadIdx.x >= (unsigned)off) ? scn[threadIdx.x - off] : 0;
        __syncthreads();
        if (threadIdx.x < 128) scn[threadIdx.x] += t;
        __syncthreads();
    }
    if (threadIdx.x < 128) {
        int excl = scn[threadIdx.x] - v;
        cur[threadIdx.x] = excl;
        if (threadIdx.x < nodes) ptr[node0 + threadIdx.x] = base + excl;
    }
    if (b == nb - 1 && threadIdx.x == 0) ptr[N] = Etot;
    __syncthreads();
    for (int i = threadIdx.x; i < count; i += 256) {
        int2 sd = bkt[base + i];
        int pos = base + atomicAdd(&cur[sd.y - node0], 1);
        csr_src[pos] = sd.x;
        float4 a = *(const float4*)&es[sd.x * 4];
        float4 bb = *(const float4*)&ed[sd.y * 4];
        union { _Float16 h[4]; uint2 u; } ww;
        ww.h[0] = (_Float16)__expf(lrelu(a.x + bb.x));
        ww.h[1] = (_Float16)__expf(lrelu(a.y + bb.y));
        ww.h[2] = (_Float16)__expf(lrelu(a.z + bb.z));
        ww.h[3] = (_Float16)__expf(lrelu(a.w + bb.w));
        *(uint2*)&w1h[(size_t)pos * 4] = ww.u;
    }
}

// ---------------------------------------------------------------------------
// GEMM2 (MFMA bf16) + fused dots2: h2b = bf16(h1e @ W2); es2/ed2 per row.
// ---------------------------------------------------------------------------
__global__ __launch_bounds__(256) void gemm2_mfma_kernel(
        const unsigned short* __restrict__ h1e, const float* __restrict__ W2,
        const float* __restrict__ a_src, const float* __restrict__ a_dst,
        unsigned short* __restrict__ h2b, float* __restrict__ es,
        float* __restrict__ ed, int N) {
    __shared__ unsigned short xs[64][136];
    __shared__ unsigned short wt[32][136];
    int tid = threadIdx.x;
    int n0 = blockIdx.x * 64;

    for (int i = tid; i < 128 * 32; i += 256) {
        int k = i >> 5, n = i & 31;
        wt[n][k] = f2b(W2[i]);
    }
    {
        const unsigned int* srcp = (const unsigned int*)(h1e + (size_t)n0 * 128);
        int rows = (N - n0) < 64 ? (N - n0) : 64;
        int maxu = rows * 64;
        for (int i = tid; i < 4096; i += 256) {
            unsigned int v = (i < maxu) ? srcp[i] : 0u;
            int r = i >> 6, cp = (i & 63) << 1;
            *(unsigned int*)&xs[r][cp] = v;
        }
    }
    __syncthreads();

    int wave = tid >> 6;
    int lane = tid & 63;
    int lrow = lane & 15;
    int quad = lane >> 4;

    short8 afr[4];
#pragma unroll
    for (int kc = 0; kc < 4; kc++)
        afr[kc] = *(const short8*)&xs[wave * 16 + lrow][kc * 32 + quad * 8];
    __syncthreads();

#pragma unroll
    for (int ct = 0; ct < 2; ct++) {
        float4v acc = {0.f, 0.f, 0.f, 0.f};
#pragma unroll
        for (int kc = 0; kc < 4; kc++) {
            short8 bfr = *(const short8*)&wt[ct * 16 + lrow][kc * 32 + quad * 8];
            acc = __builtin_amdgcn_mfma_f32_16x16x32_bf16(afr[kc], bfr, acc, 0, 0, 0);
        }
#pragma unroll
        for (int r = 0; r < 4; r++) {
            int lr = wave * 16 + quad * 4 + r;
            int grow = n0 + lr;
            unsigned short hb = f2b(acc[r]);
            xs[lr][ct * 16 + lrow] = hb;
            if (grow < N)
                h2b[(size_t)grow * 32 + ct * 16 + lrow] = hb;
        }
    }
    __syncthreads();

    // fused dots2 (1 head, 32 channels): threads 0..63 = rows
    if (tid < 64) {
        int rg = n0 + tid;
        if (rg < N) {
            float s = 0.f, d = 0.f;
#pragma unroll
            for (int c2 = 0; c2 < 16; c2++) {
                unsigned int u = *(const unsigned int*)&xs[tid][2 * c2];
                float v0 = b2f((unsigned short)(u & 0xffffu));
                float v1 = b2f((unsigned short)(u >> 16));
                float2 a = *(const float2*)&a_src[2 * c2];
                float2 b = *(const float2*)&a_dst[2 * c2];
                s += v0 * a.x + v1 * a.y;
                d += v0 * b.x + v1 * b.y;
            }
            es[rg] = s;
            ed[rg] = d;
        }
    }
}

// ---------------------------------------------------------------------------
// Aggregation layer 1: 16 lanes/node x 8 channels (uint4 = 16 B/lane),
// 4 nodes/wave, 16/block; linear fp16 weight stream (w1h).
// ---------------------------------------------------------------------------
__global__ __launch_bounds__(256) void agg1_kernel(
        const uint4* __restrict__ h1v, const _Float16* __restrict__ w1h,
        const int* __restrict__ csr, const int* __restrict__ ptr,
        const float* __restrict__ b1, uint4* __restrict__ h1e_v, int N) {
    int tid = threadIdx.x;
    int n = blockIdx.x * 16 + (tid >> 4);
    if (n >= N) return;
    int cl = tid & 15;           // 16-B granule: channels 8cl..8cl+7
    int h = cl >> 2;             // head
    int start = ptr[n], end = ptr[n + 1];
    float a0 = 0.f, a1 = 0.f, a2 = 0.f, a3 = 0.f;
    float a4 = 0.f, a5 = 0.f, a6 = 0.f, a7 = 0.f, ws = 0.f;
    int i = start;
    for (; i + 4 <= end; i += 4) {
        int s[4]; float v[4]; uint4 g[4];
#pragma unroll
        for (int k = 0; k < 4; k++) s[k] = csr[i + k];
#pragma unroll
        for (int k = 0; k < 4; k++) v[k] = (float)w1h[(size_t)(i + k) * 4 + h];
#pragma unroll
        for (int k = 0; k < 4; k++) g[k] = h1v[(s[k] << 4) + cl];
#pragma unroll
        for (int k = 0; k < 4; k++) {
            a0 += v[k] * b2f((unsigned short)(g[k].x & 0xffffu));
            a1 += v[k] * b2f((unsigned short)(g[k].x >> 16));
            a2 += v[k] * b2f((unsigned short)(g[k].y & 0xffffu));
            a3 += v[k] * b2f((unsigned short)(g[k].y >> 16));
            a4 += v[k] * b2f((unsigned short)(g[k].z & 0xffffu));
            a5 += v[k] * b2f((unsigned short)(g[k].z >> 16));
            a6 += v[k] * b2f((unsigned short)(g[k].w & 0xffffu));
            a7 += v[k] * b2f((unsigned short)(g[k].w >> 16));
            ws += v[k];
        }
    }
    for (; i < end; i++) {
        int s = csr[i];
        float v = (float)w1h[(size_t)i * 4 + h];
        uint4 g = h1v[(s << 4) + cl];
        a0 += v * b2f((unsigned short)(g.x & 0xffffu));
        a1 += v * b2f((unsigned short)(g.x >> 16));
        a2 += v * b2f((unsigned short)(g.y & 0xffffu));
        a3 += v * b2f((unsigned short)(g.y >> 16));
        a4 += v * b2f((unsigned short)(g.z & 0xffffu));
        a5 += v * b2f((unsigned short)(g.z >> 16));
        a6 += v * b2f((unsigned short)(g.w & 0xffffu));
        a7 += v * b2f((unsigned short)(g.w >> 16));
        ws += v;
    }
    float r = 1.f / ws;
    float4 bb0 = ((const float4*)b1)[cl * 2];
    float4 bb1 = ((const float4*)b1)[cl * 2 + 1];
    float o0 = a0 * r + bb0.x;
    float o1 = a1 * r + bb0.y;
    float o2 = a2 * r + bb0.z;
    float o3 = a3 * r + bb0.w;
    float o4 = a4 * r + bb1.x;
    float o5 = a5 * r + bb1.y;
    float o6 = a6 * r + bb1.z;
    float o7 = a7 * r + bb1.w;
    o0 = o0 > 0.f ? o0 : __expf(o0) - 1.f;
    o1 = o1 > 0.f ? o1 : __expf(o1) - 1.f;
    o2 = o2 > 0.f ? o2 : __expf(o2) - 1.f;
    o3 = o3 > 0.f ? o3 : __expf(o3) - 1.f;
    o4 = o4 > 0.f ? o4 : __expf(o4) - 1.f;
    o5 = o5 > 0.f ? o5 : __expf(o5) - 1.f;
    o6 = o6 > 0.f ? o6 : __expf(o6) - 1.f;
    o7 = o7 > 0.f ? o7 : __expf(o7) - 1.f;
    uint4 outv;
    outv.x = (unsigned int)f2b(o0) | ((unsigned int)f2b(o1) << 16);
    outv.y = (unsigned int)f2b(o2) | ((unsigned int)f2b(o3) << 16);
    outv.z = (unsigned int)f2b(o4) | ((unsigned int)f2b(o5) << 16);
    outv.w = (unsigned int)f2b(o6) | ((unsigned int)f2b(o7) << 16);
    h1e_v[(n << 4) + cl] = outv;
}

// ---------------------------------------------------------------------------
// Aggregation layer 2: 8 lanes/node x 4 channels (uint2 = one 64-B line per
// edge), 8 nodes/wave, 32/block; unroll x8; inline exp weights.
// ---------------------------------------------------------------------------
__global__ __launch_bounds__(256) void agg2_kernel(
        const uint2* __restrict__ h2v, const float* __restrict__ es,
        const float* __restrict__ ed, const int* __restrict__ csr,
        const int* __restrict__ ptr, const float* __restrict__ b2,
        float* __restrict__ out, int N) {
    int tid = threadIdx.x;
    int n = blockIdx.x * 32 + (tid >> 3);
    if (n >= N) return;
    int cl = tid & 7;            // channels 4cl..4cl+3
    float edl = ed[n];
    int start = ptr[n], end = ptr[n + 1];
    float a0 = 0.f, a1 = 0.f, a2 = 0.f, a3 = 0.f, ws = 0.f;
    int i = start;
    for (; i + 8 <= end; i += 8) {
        int s[8]; float e[8]; uint2 g[8];
#pragma unroll
        for (int k = 0; k < 8; k++) s[k] = csr[i + k];
#pragma unroll
        for (int k = 0; k < 8; k++) e[k] = es[s[k]];
#pragma unroll
        for (int k = 0; k < 8; k++) g[k] = h2v[(s[k] << 3) + cl];
#pragma unroll
        for (int k = 0; k < 8; k++) {
            float v = __expf(lrelu(e[k] + edl));
            a0 += v * b2f((unsigned short)(g[k].x & 0xffffu));
            a1 += v * b2f((unsigned short)(g[k].x >> 16));
            a2 += v * b2f((unsigned short)(g[k].y & 0xffffu));
            a3 += v * b2f((unsigned short)(g[k].y >> 16));
            ws += v;
        }
    }
    for (; i < end; i++) {
        int s = csr[i];
        float v = __expf(lrelu(es[s] + edl));
        uint2 g = h2v[(s << 3) + cl];
        a0 += v * b2f((unsigned short)(g.x & 0xffffu));
        a1 += v * b2f((unsigned short)(g.x >> 16));
        a2 += v * b2f((unsigned short)(g.y & 0xffffu));
        a3 += v * b2f((unsigned short)(g.y >> 16));
        ws += v;
    }
    float r = 1.f / ws;
    float4 bb = ((const float4*)b2)[cl];
    float4 o;
    o.x = a0 * r + bb.x;
    o.y = a1 * r + bb.y;
    o.z = a2 * r + bb.z;
    o.w = a3 * r + bb.w;
    ((float4*)out)[(size_t)n * 8 + cl] = o;
}

// ---------------------------------------------------------------------------
extern "C" void kernel_launch(void* const* d_in, const int* in_sizes, int n_in,
                              void* d_out, int out_size, void* d_ws, size_t ws_size,
                              hipStream_t stream) {
    const float* x      = (const float*)d_in[0];
    const int*   ei     = (const int*)  d_in[1];
    const float* W1     = (const float*)d_in[2];
    const float* a_src1 = (const float*)d_in[3];
    const float* a_dst1 = (const float*)d_in[4];
    const float* b1     = (const float*)d_in[5];
    const float* W2     = (const float*)d_in[6];
    const float* a_src2 = (const float*)d_in[7];
    const float* a_dst2 = (const float*)d_in[8];
    const float* b2     = (const float*)d_in[9];
    float* outp = (float*)d_out;

    const int N = in_sizes[0] / 128;   // 50000
    const int E = in_sizes[1] / 2;     // 800000
    const int Etot = E + N;            // 850000

    const int* src = ei;
    const int* dst = ei + E;

    const int nb    = (N + 127) >> 7;                // 391 buckets
    const int chunk = (Etot + NBLK - 1) / NBLK;      // 1661
    const int M = nb * NBLK;                         // 200192 scan elements
    const int nbA = (M + 1023) / 1024;               // 196

    // workspace layout (bytes); total ~48.8 MB
    char* w = (char*)d_ws;
    unsigned short* h1b = (unsigned short*)(w + 0);          // 12,800,000
    unsigned short* h1e = (unsigned short*)(w + 12800000);   // 12,800,000
    unsigned short* h2b = (unsigned short*)(w + 25600000);   //  3,200,000
    float* es1  = (float*)(w + 28800000);                    //    800,000
    float* ed1  = (float*)(w + 29600000);                    //    800,000
    float* es2  = (float*)(w + 30400000);                    //    200,000
    float* ed2  = (float*)(w + 30600000);                    //    200,000
    int*   ptr  = (int*)  (w + 30800000);                    //    200,064
    int*   bsum = (int*)  (w + 31000064);                    //      1,024
    int*   cnt  = (int*)  (w + 31001088);                    //    800,768
    int*   csr_src = (int*)(w + 31801856);                   //  3,400,000
    int2*  bkt  = (int2*) (w + 35201856);                    //  6,800,000
    _Float16* w1h = (_Float16*)(w + 42001856);               //  6,800,000 -> 48,801,856

    // --- Layer-1 GEMM + fused dots1 + fused hist ---
    gemm1_mfma_kernel<<<(N + 63) / 64, 256, 0, stream>>>(x, W1, a_src1, a_dst1,
                                                         h1b, es1, ed1, N,
                                                         dst, E, Etot, nb, chunk,
                                                         cnt);

    // --- CSR build: scanA -> scanB -> partition -> finalize ---
    scanA_kernel<<<nbA, 1024, 0, stream>>>(cnt, bsum, M);
    scanB_kernel<<<1, 256, 0, stream>>>(bsum, nbA);
    partition_kernel<<<NBLK, 256, 0, stream>>>(src, dst, E, Etot, nb, chunk,
                                               cnt, bsum, bkt);
    finalize_kernel<<<nb, 256, 0, stream>>>(bkt, cnt, bsum, nb, es1, ed1,
                                            ptr, csr_src, w1h, N, Etot);

    // --- Layer 1 aggregate (linear fp16 weight stream) ---
    agg1_kernel<<<(N + 15) / 16, 256, 0, stream>>>((const uint4*)h1b, w1h,
                                                   csr_src, ptr, b1,
                                                   (uint4*)h1e, N);

    // --- Layer 2: GEMM + fused dots, then aggregate with inline weights ---
    gemm2_mfma_kernel<<<(N + 63) / 64, 256, 0, stream>>>(h1e, W2, a_src2, a_dst2,
                                                         h2b, es2, ed2, N);
    agg2_kernel<<<(N + 31) / 32, 256, 0, stream>>>((const uint2*)h2b, es2, ed2,
                                                   csr_src, ptr, b2, outp, N);
}